// Round 1
// baseline (1442.202 us; speedup 1.0000x reference)
//
#include <hip/hip_runtime.h>

#define N_ 8
#define C_ 64
#define H_ 128
#define W_ 512
#define CO_ 64
#define HW_ (H_*W_)
#define NTAP 9

typedef short s8v __attribute__((ext_vector_type(8)));   // 8 bf16 in 4 VGPRs
typedef float f16v __attribute__((ext_vector_type(16))); // 32x32 acc
typedef float f2v __attribute__((ext_vector_type(2)));   // (dy,dx) pair

__device__ __forceinline__ unsigned short f2bf(float f) {
    unsigned u = __float_as_uint(f);
    u += 0x7FFF + ((u >> 16) & 1u);     // round-to-nearest-even
    return (unsigned short)(u >> 16);
}
__device__ __forceinline__ unsigned packbf(float a, float b) {
    return (unsigned)f2bf(a) | ((unsigned)f2bf(b) << 16);
}

// ---------------------------------------------------------------------------
// Prep: w_def [co][c][3][3] -> wTb bf16 [t][co][c]  (B-operand: k=c contiguous)
//       w_off [18][c][3][3] -> wOb bf16 [t][32][c]  (och padded 18->32 w/ 0)
// ---------------------------------------------------------------------------
__global__ void k_prep_w(const float* __restrict__ w_def,
                         const float* __restrict__ w_off,
                         unsigned short* __restrict__ wTb,
                         unsigned short* __restrict__ wOb) {
    int idx = blockIdx.x * 256 + threadIdx.x;
    if (idx < NTAP * CO_ * C_) {
        int t = idx / (CO_ * C_);
        int r = idx % (CO_ * C_);
        int co = r / C_, c = r % C_;
        wTb[idx] = f2bf(w_def[(co * C_ + c) * NTAP + t]);
    }
    if (idx < NTAP * 32 * C_) {
        int t = idx / (32 * C_);
        int r = idx % (32 * C_);
        int oc = r / C_, c = r % C_;
        float v = (oc < 18) ? w_off[(oc * C_ + c) * NTAP + t] : 0.f;
        wOb[idx] = f2bf(v);
    }
}

// ---------------------------------------------------------------------------
// Offset conv as MFMA GEMM: M=128px/block, K=576 (9 taps x 64c), N=32 (18 used)
// B-fragments read directly from global wOb (36 KB, L1/L2 resident) -- no LDS
// staging. LDS = S only (17408 B) -> 8 blocks/CU.
// ---------------------------------------------------------------------------
__global__ __launch_bounds__(256, 8) void k_off_mfma(
        const float* __restrict__ x,
        const unsigned short* __restrict__ wOb,
        const float* __restrict__ b_off,
        float* __restrict__ off_ws) {
    __shared__ __align__(16) char smem[17408];
    char* S  = smem;              // [128][68] bf16 = 17408 B
    float* E = (float*)smem;      // [128][33] f32 = 16896 B (epilogue reuse)

    int tid = threadIdx.x;
    int b = blockIdx.x;
    int n = b & 7;
    int lidx = b >> 3;
    int y = lidx >> 2;
    int xb = (lidx & 3) << 7;
    int lane = tid & 63, wave = tid >> 6;
    int p = tid & 127, cg = tid >> 7;
    int la = lane & 31, kh = lane >> 5;

    f16v acc;
    #pragma unroll
    for (int r = 0; r < 16; r++) acc[r] = 0.f;

    const float* xn = x + (size_t)n * C_ * HW_;

    for (int t = 0; t < NTAP; t++) {
        int yy = y + (t / 3) - 1;
        if (yy < 0 || yy >= H_) continue;   // block-uniform
        __syncthreads();
        // sample S: plain shifted read, zero OOB; lanes along x -> coalesced
        {
            int xx = xb + p + (t % 3) - 1;
            bool ok = (xx >= 0) && (xx < W_);
            const float* xr = xn + (size_t)(cg * 32) * HW_ + yy * W_;
            char* sp = S + p * 136 + (cg * 32) * 2;
            #pragma unroll
            for (int u = 0; u < 16; u++) {
                float v0 = ok ? xr[xx] : 0.f;
                float v1 = ok ? xr[HW_ + xx] : 0.f;
                *(unsigned*)sp = packbf(v0, v1);
                sp += 4;
                xr += 2 * HW_;
            }
        }
        __syncthreads();
        // MFMA: wave w -> px block w*32; och 0..31; B direct from global
        {
            const char* ap = S + (wave * 32 + la) * 136 + kh * 16;
            const char* gb = (const char*)wOb + t * 4096 + la * 128 + kh * 16;
            #pragma unroll
            for (int ks = 0; ks < 4; ks++) {
                s8v a, bf;
                *(long*)&a = *(const long*)ap;
                *((long*)&a + 1) = *(const long*)(ap + 8);
                bf = *(const s8v*)(gb + ks * 32);
                ap += 32;
                acc = __builtin_amdgcn_mfma_f32_32x32x16_bf16(a, bf, acc, 0, 0, 0);
            }
        }
    }
    __syncthreads();
    // epilogue: C/D layout col=lane&31 (och), row=(r&3)+8*(r>>2)+4*(lane>>5) (px)
    {
        int lh = lane >> 5;
        #pragma unroll
        for (int r = 0; r < 16; r++) {
            int pxl = wave * 32 + (r & 3) + 8 * (r >> 2) + 4 * lh;
            E[pxl * 33 + la] = acc[r];
        }
    }
    __syncthreads();
    {
        size_t base = ((size_t)(n * H_ + y) * W_ + xb) * 18;
        #pragma unroll
        for (int k = 0; k < 9; k++) {
            int f = tid + k * 256;
            int pp = f / 18, oc = f % 18;
            __builtin_nontemporal_store(E[pp * 33 + oc] + b_off[oc],
                                        &off_ws[base + f]);
        }
    }
}

// ---------------------------------------------------------------------------
// Bilinear metadata: 4 weights (validity folded) + 4 clamped linear offsets
// ---------------------------------------------------------------------------
__device__ __forceinline__ void bilin_meta(float py, float px,
        float& w00, float& w01, float& w10, float& w11,
        int& o00, int& o01, int& o10, int& o11) {
    float fy0 = floorf(py), fx0 = floorf(px);
    int iy0 = (int)fy0, ix0 = (int)fx0;
    int iy1 = iy0 + 1,  ix1 = ix0 + 1;
    float ly = py - fy0, lx = px - fx0;
    float hy = 1.f - ly, hx = 1.f - lx;
    bool y0ok = (iy0 >= 0) && (iy0 < H_);
    bool y1ok = (iy1 >= 0) && (iy1 < H_);
    bool x0ok = (ix0 >= 0) && (ix0 < W_);
    bool x1ok = (ix1 >= 0) && (ix1 < W_);
    w00 = hy * hx * ((y0ok && x0ok) ? 1.f : 0.f);
    w01 = hy * lx * ((y0ok && x1ok) ? 1.f : 0.f);
    w10 = ly * hx * ((y1ok && x0ok) ? 1.f : 0.f);
    w11 = ly * lx * ((y1ok && x1ok) ? 1.f : 0.f);
    int y0c = min(max(iy0, 0), H_ - 1), y1c = min(max(iy1, 0), H_ - 1);
    int x0c = min(max(ix0, 0), W_ - 1), x1c = min(max(ix1, 0), W_ - 1);
    o00 = y0c * W_ + x0c; o01 = y0c * W_ + x1c;
    o10 = y1c * W_ + x0c; o11 = y1c * W_ + x1c;
}

// ---------------------------------------------------------------------------
// Deformable conv as fused sample+MFMA GEMM: M=128px/block, K=576, N=64.
// Per tap: sample bilinear S[128][64c] bf16 -> LDS; B-fragments direct from
// global wTb (72 KB, cache resident); 4 waves x (32px x 64co) via 2 MFMA/K.
// LDS = S only (17408 B) -> 7 blocks/CU (launch_bounds cap, VGPR<=73).
// ---------------------------------------------------------------------------
__global__ __launch_bounds__(256, 7) void k_deform(
        const float* __restrict__ x,
        const float* __restrict__ off_ws,
        const unsigned short* __restrict__ wTb,
        const float* __restrict__ b_def,
        float* __restrict__ out) {
    __shared__ __align__(16) char smem[17408];
    char* S  = smem;              // [128][68] bf16 = 17408 B
    float* E = (float*)smem;      // [128][33] f32 = 16896 B (epilogue, 2 passes)

    int tid = threadIdx.x;
    int b = blockIdx.x;
    int n = b & 7;                 // image <-> XCD for L2 locality
    int lidx = b >> 3;
    int y = lidx >> 2;
    int xb = (lidx & 3) << 7;
    int lane = tid & 63, wave = tid >> 6;
    int p = tid & 127, cg = tid >> 7;
    int la = lane & 31, kh = lane >> 5;

    f16v acc0, acc1;
    #pragma unroll
    for (int r = 0; r < 16; r++) { acc0[r] = 0.f; acc1[r] = 0.f; }

    const float* xn = x + (size_t)n * C_ * HW_;
    size_t pix = (size_t)(n * H_ + y) * W_ + xb + p;
    const f2v* offp = (const f2v*)off_ws + pix * 9;

    for (int t = 0; t < NTAP; t++) {
        __syncthreads();           // S readers from prev tap done
        // bilinear meta (once per px per tap; 2x redundant across cg)
        f2v od = __builtin_nontemporal_load(offp + t);
        float py = (float)(y + (t / 3) - 1) + od[0];
        float pxf = (float)(xb + p + (t % 3) - 1) + od[1];
        float w00, w01, w10, w11;
        int o00, o01, o10, o11;
        bilin_meta(py, pxf, w00, w01, w10, w11, o00, o01, o10, o11);

        // sample 32 channels: 4 near-coalesced gathers + 4 FMA each
        {
            const float* xc = xn + (size_t)(cg * 32) * HW_;
            char* sp = S + p * 136 + (cg * 32) * 2;
            #pragma unroll
            for (int u = 0; u < 16; u++) {
                float v0 = w00 * xc[o00];
                v0 = fmaf(w01, xc[o01], v0);
                v0 = fmaf(w10, xc[o10], v0);
                v0 = fmaf(w11, xc[o11], v0);
                const float* xc1 = xc + HW_;
                float v1 = w00 * xc1[o00];
                v1 = fmaf(w01, xc1[o01], v1);
                v1 = fmaf(w10, xc1[o10], v1);
                v1 = fmaf(w11, xc1[o11], v1);
                *(unsigned*)sp = packbf(v0, v1);
                sp += 4;
                xc += 2 * HW_;
            }
        }
        __syncthreads();
        // MFMA; B fragments straight from global (L1/L2-resident 72 KB table)
        {
            const char* ap = S + (wave * 32 + la) * 136 + kh * 16;
            const char* gb = (const char*)wTb + t * 8192 + la * 128 + kh * 16;
            #pragma unroll
            for (int ks = 0; ks < 4; ks++) {
                s8v a, b0, b1;
                *(long*)&a = *(const long*)ap;
                *((long*)&a + 1) = *(const long*)(ap + 8);
                b0 = *(const s8v*)(gb + ks * 32);
                b1 = *(const s8v*)(gb + 4096 + ks * 32);
                ap += 32;
                acc0 = __builtin_amdgcn_mfma_f32_32x32x16_bf16(a, b0, acc0, 0, 0, 0);
                acc1 = __builtin_amdgcn_mfma_f32_32x32x16_bf16(a, b1, acc1, 0, 0, 0);
            }
        }
    }
    __syncthreads();
    // two-pass epilogue through E[128][33]: acc0 (co 0..31), then acc1 (32..63)
    {
        int lh = lane >> 5;
        #pragma unroll
        for (int r = 0; r < 16; r++) {
            int pxl = wave * 32 + (r & 3) + 8 * (r >> 2) + 4 * lh;
            E[pxl * 33 + la] = acc0[r];
        }
        __syncthreads();
        {
            int p0 = tid & 63;
            #pragma unroll
            for (int cb = 0; cb < 8; cb++) {
                int co = (cb << 2) + (tid >> 6);    // 0..31
                float bv = b_def[co];
                size_t ob = ((size_t)(n * CO_ + co) * H_ + y) * W_ + xb;
                __builtin_nontemporal_store(E[p0 * 33 + co] + bv, &out[ob + p0]);
                __builtin_nontemporal_store(E[(p0 + 64) * 33 + co] + bv,
                                            &out[ob + p0 + 64]);
            }
        }
        __syncthreads();
        #pragma unroll
        for (int r = 0; r < 16; r++) {
            int pxl = wave * 32 + (r & 3) + 8 * (r >> 2) + 4 * lh;
            E[pxl * 33 + la] = acc1[r];
        }
        __syncthreads();
        {
            int p0 = tid & 63;
            #pragma unroll
            for (int cb = 0; cb < 8; cb++) {
                int cl = (cb << 2) + (tid >> 6);    // 0..31
                int co = 32 + cl;
                float bv = b_def[co];
                size_t ob = ((size_t)(n * CO_ + co) * H_ + y) * W_ + xb;
                __builtin_nontemporal_store(E[p0 * 33 + cl] + bv, &out[ob + p0]);
                __builtin_nontemporal_store(E[(p0 + 64) * 33 + cl] + bv,
                                            &out[ob + p0 + 64]);
            }
        }
    }
}

// ---------------------------------------------------------------------------
extern "C" void kernel_launch(void* const* d_in, const int* in_sizes, int n_in,
                              void* d_out, int out_size, void* d_ws, size_t ws_size,
                              hipStream_t stream) {
    const float* x     = (const float*)d_in[0];
    const float* w_off = (const float*)d_in[1];
    const float* b_off = (const float*)d_in[2];
    const float* w_def = (const float*)d_in[3];
    const float* b_def = (const float*)d_in[4];
    float* out = (float*)d_out;

    // ws: wTb bf16 @0 (73728 B), wOb bf16 @80K (36864 B), off_ws @256K (37.7 MB)
    unsigned short* wTb = (unsigned short*)d_ws;
    unsigned short* wOb = (unsigned short*)((char*)d_ws + 80 * 1024);
    float* off_ws       = (float*)((char*)d_ws + 256 * 1024);

    hipLaunchKernelGGL(k_prep_w, dim3(144), dim3(256), 0, stream,
                       w_def, w_off, wTb, wOb);
    hipLaunchKernelGGL(k_off_mfma, dim3(4096), dim3(256), 0, stream,
                       x, wOb, b_off, off_ws);
    hipLaunchKernelGGL(k_deform, dim3(4096), dim3(256), 0, stream,
                       x, off_ws, wTb, b_def, out);
}

// Round 2
// 1351.474 us; speedup vs baseline: 1.0671x; 1.0671x over previous
//
#include <hip/hip_runtime.h>

#define N_ 8
#define C_ 64
#define H_ 128
#define W_ 512
#define CO_ 64
#define HW_ (H_*W_)
#define NTAP 9

typedef short s8v __attribute__((ext_vector_type(8)));   // 8 bf16 in 4 VGPRs
typedef float f16v __attribute__((ext_vector_type(16))); // 32x32 acc
typedef float f2v __attribute__((ext_vector_type(2)));   // (dy,dx) pair

__device__ __forceinline__ unsigned short f2bf(float f) {
    unsigned u = __float_as_uint(f);
    u += 0x7FFF + ((u >> 16) & 1u);     // round-to-nearest-even
    return (unsigned short)(u >> 16);
}
__device__ __forceinline__ unsigned packbf(float a, float b) {
    return (unsigned)f2bf(a) | ((unsigned)f2bf(b) << 16);
}

// ---------------------------------------------------------------------------
// Prep: w_def [co][c][3][3] -> wTb bf16 [t][co][c]  (B-operand: k=c contiguous)
//       w_off [18][c][3][3] -> wOb bf16 [t][32][c]  (och padded 18->32 w/ 0)
// ---------------------------------------------------------------------------
__global__ void k_prep_w(const float* __restrict__ w_def,
                         const float* __restrict__ w_off,
                         unsigned short* __restrict__ wTb,
                         unsigned short* __restrict__ wOb) {
    int idx = blockIdx.x * 256 + threadIdx.x;
    if (idx < NTAP * CO_ * C_) {
        int t = idx / (CO_ * C_);
        int r = idx % (CO_ * C_);
        int co = r / C_, c = r % C_;
        wTb[idx] = f2bf(w_def[(co * C_ + c) * NTAP + t]);
    }
    if (idx < NTAP * 32 * C_) {
        int t = idx / (32 * C_);
        int r = idx % (32 * C_);
        int oc = r / C_, c = r % C_;
        float v = (oc < 18) ? w_off[(oc * C_ + c) * NTAP + t] : 0.f;
        wOb[idx] = f2bf(v);
    }
}

// ---------------------------------------------------------------------------
// Offset conv as MFMA GEMM: M=128px/block, K=576 (9 taps x 64c), N=32 (18 used)
// B-fragments read directly from global wOb (36 KB, L1/L2 resident) -- no LDS
// staging. LDS = S only (17408 B).
// ---------------------------------------------------------------------------
__global__ __launch_bounds__(256, 8) void k_off_mfma(
        const float* __restrict__ x,
        const unsigned short* __restrict__ wOb,
        const float* __restrict__ b_off,
        float* __restrict__ off_ws) {
    __shared__ __align__(16) char smem[17408];
    char* S  = smem;              // [128][68] bf16 = 17408 B
    float* E = (float*)smem;      // [128][33] f32 = 16896 B (epilogue reuse)

    int tid = threadIdx.x;
    int b = blockIdx.x;
    int n = b & 7;
    int lidx = b >> 3;
    int y = lidx >> 2;
    int xb = (lidx & 3) << 7;
    int lane = tid & 63, wave = tid >> 6;
    int p = tid & 127, cg = tid >> 7;
    int la = lane & 31, kh = lane >> 5;

    f16v acc;
    #pragma unroll
    for (int r = 0; r < 16; r++) acc[r] = 0.f;

    const float* xn = x + (size_t)n * C_ * HW_;

    for (int t = 0; t < NTAP; t++) {
        int yy = y + (t / 3) - 1;
        if (yy < 0 || yy >= H_) continue;   // block-uniform
        __syncthreads();
        // sample S: plain shifted read, zero OOB; lanes along x -> coalesced
        {
            int xx = xb + p + (t % 3) - 1;
            bool ok = (xx >= 0) && (xx < W_);
            const float* xr = xn + (size_t)(cg * 32) * HW_ + yy * W_;
            char* sp = S + p * 136 + (cg * 32) * 2;
            #pragma unroll
            for (int u = 0; u < 16; u++) {
                float v0 = ok ? xr[xx] : 0.f;
                float v1 = ok ? xr[HW_ + xx] : 0.f;
                *(unsigned*)sp = packbf(v0, v1);
                sp += 4;
                xr += 2 * HW_;
            }
        }
        __syncthreads();
        // MFMA: wave w -> px block w*32; och 0..31; B direct from global
        {
            const char* ap = S + (wave * 32 + la) * 136 + kh * 16;
            const char* gb = (const char*)wOb + t * 4096 + la * 128 + kh * 16;
            #pragma unroll
            for (int ks = 0; ks < 4; ks++) {
                s8v a, bf;
                *(long*)&a = *(const long*)ap;
                *((long*)&a + 1) = *(const long*)(ap + 8);
                bf = *(const s8v*)(gb + ks * 32);
                ap += 32;
                acc = __builtin_amdgcn_mfma_f32_32x32x16_bf16(a, bf, acc, 0, 0, 0);
            }
        }
    }
    __syncthreads();
    // epilogue: C/D layout col=lane&31 (och), row=(r&3)+8*(r>>2)+4*(lane>>5) (px)
    {
        int lh = lane >> 5;
        #pragma unroll
        for (int r = 0; r < 16; r++) {
            int pxl = wave * 32 + (r & 3) + 8 * (r >> 2) + 4 * lh;
            E[pxl * 33 + la] = acc[r];
        }
    }
    __syncthreads();
    {
        size_t base = ((size_t)(n * H_ + y) * W_ + xb) * 18;
        #pragma unroll
        for (int k = 0; k < 9; k++) {
            int f = tid + k * 256;
            int pp = f / 18, oc = f % 18;
            off_ws[base + f] = E[pp * 33 + oc] + b_off[oc];
        }
    }
}

// ---------------------------------------------------------------------------
// Bilinear metadata: 4 weights (validity folded) + 4 clamped linear offsets
// ---------------------------------------------------------------------------
__device__ __forceinline__ void bilin_meta(float py, float px,
        float& w00, float& w01, float& w10, float& w11,
        int& o00, int& o01, int& o10, int& o11) {
    float fy0 = floorf(py), fx0 = floorf(px);
    int iy0 = (int)fy0, ix0 = (int)fx0;
    int iy1 = iy0 + 1,  ix1 = ix0 + 1;
    float ly = py - fy0, lx = px - fx0;
    float hy = 1.f - ly, hx = 1.f - lx;
    bool y0ok = (iy0 >= 0) && (iy0 < H_);
    bool y1ok = (iy1 >= 0) && (iy1 < H_);
    bool x0ok = (ix0 >= 0) && (ix0 < W_);
    bool x1ok = (ix1 >= 0) && (ix1 < W_);
    w00 = hy * hx * ((y0ok && x0ok) ? 1.f : 0.f);
    w01 = hy * lx * ((y0ok && x1ok) ? 1.f : 0.f);
    w10 = ly * hx * ((y1ok && x0ok) ? 1.f : 0.f);
    w11 = ly * lx * ((y1ok && x1ok) ? 1.f : 0.f);
    int y0c = min(max(iy0, 0), H_ - 1), y1c = min(max(iy1, 0), H_ - 1);
    int x0c = min(max(ix0, 0), W_ - 1), x1c = min(max(ix1, 0), W_ - 1);
    o00 = y0c * W_ + x0c; o01 = y0c * W_ + x1c;
    o10 = y1c * W_ + x0c; o11 = y1c * W_ + x1c;
}

// ---------------------------------------------------------------------------
// Deformable conv as fused sample+MFMA GEMM: M=128px/block, K=576, N=64.
// Per tap: sample bilinear S[128][64c] bf16 -> LDS; B-fragments direct from
// global wTb (72 KB, cache resident); 4 waves x (32px x 64co) via 2 MFMA/K.
// LDS = S only (17408 B). launch_bounds(256,5): 102-reg cap -> ~70 VGPR free
// after 32 AGPR acc, enough for 32-wide gather load batches (latency hiding).
// ---------------------------------------------------------------------------
__global__ __launch_bounds__(256, 5) void k_deform(
        const float* __restrict__ x,
        const float* __restrict__ off_ws,
        const unsigned short* __restrict__ wTb,
        const float* __restrict__ b_def,
        float* __restrict__ out) {
    __shared__ __align__(16) char smem[17408];
    char* S  = smem;              // [128][68] bf16 = 17408 B
    float* E = (float*)smem;      // [128][33] f32 = 16896 B (epilogue, 2 passes)

    int tid = threadIdx.x;
    int b = blockIdx.x;
    int n = b & 7;                 // image <-> XCD for L2 locality
    int lidx = b >> 3;
    int y = lidx >> 2;
    int xb = (lidx & 3) << 7;
    int lane = tid & 63, wave = tid >> 6;
    int p = tid & 127, cg = tid >> 7;
    int la = lane & 31, kh = lane >> 5;

    f16v acc0, acc1;
    #pragma unroll
    for (int r = 0; r < 16; r++) { acc0[r] = 0.f; acc1[r] = 0.f; }

    const float* xn = x + (size_t)n * C_ * HW_;
    size_t pix = (size_t)(n * H_ + y) * W_ + xb + p;
    const f2v* offp = (const f2v*)off_ws + pix * 9;

    for (int t = 0; t < NTAP; t++) {
        // bilinear meta BEFORE the barrier: its load latency hides under sync
        f2v od = offp[t];
        float py = (float)(y + (t / 3) - 1) + od[0];
        float pxf = (float)(xb + p + (t % 3) - 1) + od[1];
        float w00, w01, w10, w11;
        int o00, o01, o10, o11;
        bilin_meta(py, pxf, w00, w01, w10, w11, o00, o01, o10, o11);
        const float* xc0 = xn + (size_t)(cg * 32) * HW_;
        char* sp = S + p * 136 + (cg * 32) * 2;

        __syncthreads();           // S readers from prev tap done
        // sample 32 channels in 4 groups of 8; 32 gather loads issued per
        // group before any FMA -> deep in-flight queue (latency hiding)
        #pragma unroll
        for (int g = 0; g < 4; g++) {
            float a00[8], a01[8], a10[8], a11[8];
            #pragma unroll
            for (int c = 0; c < 8; c++) {
                const float* xq = xc0 + (size_t)(g * 8 + c) * HW_;
                a00[c] = xq[o00]; a01[c] = xq[o01];
                a10[c] = xq[o10]; a11[c] = xq[o11];
            }
            #pragma unroll
            for (int c = 0; c < 8; c += 2) {
                float v0 = w00 * a00[c];
                v0 = fmaf(w01, a01[c], v0);
                v0 = fmaf(w10, a10[c], v0);
                v0 = fmaf(w11, a11[c], v0);
                float v1 = w00 * a00[c + 1];
                v1 = fmaf(w01, a01[c + 1], v1);
                v1 = fmaf(w10, a10[c + 1], v1);
                v1 = fmaf(w11, a11[c + 1], v1);
                *(unsigned*)(sp + g * 16 + (c >> 1) * 4) = packbf(v0, v1);
            }
        }
        __syncthreads();
        // MFMA; B fragments straight from global (L1/L2-resident 72 KB table)
        {
            const char* ap = S + (wave * 32 + la) * 136 + kh * 16;
            const char* gb = (const char*)wTb + t * 8192 + la * 128 + kh * 16;
            #pragma unroll
            for (int ks = 0; ks < 4; ks++) {
                s8v a, b0, b1;
                *(long*)&a = *(const long*)ap;
                *((long*)&a + 1) = *(const long*)(ap + 8);
                b0 = *(const s8v*)(gb + ks * 32);
                b1 = *(const s8v*)(gb + 4096 + ks * 32);
                ap += 32;
                acc0 = __builtin_amdgcn_mfma_f32_32x32x16_bf16(a, b0, acc0, 0, 0, 0);
                acc1 = __builtin_amdgcn_mfma_f32_32x32x16_bf16(a, b1, acc1, 0, 0, 0);
            }
        }
    }
    __syncthreads();
    // two-pass epilogue through E[128][33]: acc0 (co 0..31), then acc1 (32..63)
    {
        int lh = lane >> 5;
        #pragma unroll
        for (int r = 0; r < 16; r++) {
            int pxl = wave * 32 + (r & 3) + 8 * (r >> 2) + 4 * lh;
            E[pxl * 33 + la] = acc0[r];
        }
        __syncthreads();
        {
            int p0 = tid & 63;
            #pragma unroll
            for (int cb = 0; cb < 8; cb++) {
                int co = (cb << 2) + (tid >> 6);    // 0..31
                float bv = b_def[co];
                size_t ob = ((size_t)(n * CO_ + co) * H_ + y) * W_ + xb;
                out[ob + p0]      = E[p0 * 33 + co] + bv;
                out[ob + p0 + 64] = E[(p0 + 64) * 33 + co] + bv;
            }
        }
        __syncthreads();
        #pragma unroll
        for (int r = 0; r < 16; r++) {
            int pxl = wave * 32 + (r & 3) + 8 * (r >> 2) + 4 * lh;
            E[pxl * 33 + la] = acc1[r];
        }
        __syncthreads();
        {
            int p0 = tid & 63;
            #pragma unroll
            for (int cb = 0; cb < 8; cb++) {
                int cl = (cb << 2) + (tid >> 6);    // 0..31
                int co = 32 + cl;
                float bv = b_def[co];
                size_t ob = ((size_t)(n * CO_ + co) * H_ + y) * W_ + xb;
                out[ob + p0]      = E[p0 * 33 + cl] + bv;
                out[ob + p0 + 64] = E[(p0 + 64) * 33 + cl] + bv;
            }
        }
    }
}

// ---------------------------------------------------------------------------
extern "C" void kernel_launch(void* const* d_in, const int* in_sizes, int n_in,
                              void* d_out, int out_size, void* d_ws, size_t ws_size,
                              hipStream_t stream) {
    const float* x     = (const float*)d_in[0];
    const float* w_off = (const float*)d_in[1];
    const float* b_off = (const float*)d_in[2];
    const float* w_def = (const float*)d_in[3];
    const float* b_def = (const float*)d_in[4];
    float* out = (float*)d_out;

    // ws: wTb bf16 @0 (73728 B), wOb bf16 @80K (36864 B), off_ws @256K (37.7 MB)
    unsigned short* wTb = (unsigned short*)d_ws;
    unsigned short* wOb = (unsigned short*)((char*)d_ws + 80 * 1024);
    float* off_ws       = (float*)((char*)d_ws + 256 * 1024);

    hipLaunchKernelGGL(k_prep_w, dim3(144), dim3(256), 0, stream,
                       w_def, w_off, wTb, wOb);
    hipLaunchKernelGGL(k_off_mfma, dim3(4096), dim3(256), 0, stream,
                       x, wOb, b_off, off_ws);
    hipLaunchKernelGGL(k_deform, dim3(4096), dim3(256), 0, stream,
                       x, off_ws, wTb, b_def, out);
}

// Round 3
// 1324.927 us; speedup vs baseline: 1.0885x; 1.0200x over previous
//
#include <hip/hip_runtime.h>

#define N_ 8
#define C_ 64
#define H_ 128
#define W_ 512
#define CO_ 64
#define HW_ (H_*W_)
#define NTAP 9

typedef short s8v __attribute__((ext_vector_type(8)));   // 8 bf16 in 4 VGPRs
typedef float f16v __attribute__((ext_vector_type(16))); // 32x32 acc
typedef float f2v __attribute__((ext_vector_type(2)));   // (dy,dx) pair

__device__ __forceinline__ unsigned short f2bf(float f) {
    unsigned u = __float_as_uint(f);
    u += 0x7FFF + ((u >> 16) & 1u);     // round-to-nearest-even
    return (unsigned short)(u >> 16);
}
__device__ __forceinline__ unsigned packbf(float a, float b) {
    return (unsigned)f2bf(a) | ((unsigned)f2bf(b) << 16);
}

// ---------------------------------------------------------------------------
// Prep: w_def [co][c][3][3] -> wTb bf16 [t][co][c]  (B-operand: k=c contiguous)
//       w_off [18][c][3][3] -> wOb bf16 [t][32][c]  (och padded 18->32 w/ 0)
// ---------------------------------------------------------------------------
__global__ void k_prep_w(const float* __restrict__ w_def,
                         const float* __restrict__ w_off,
                         unsigned short* __restrict__ wTb,
                         unsigned short* __restrict__ wOb) {
    int idx = blockIdx.x * 256 + threadIdx.x;
    if (idx < NTAP * CO_ * C_) {
        int t = idx / (CO_ * C_);
        int r = idx % (CO_ * C_);
        int co = r / C_, c = r % C_;
        wTb[idx] = f2bf(w_def[(co * C_ + c) * NTAP + t]);
    }
    if (idx < NTAP * 32 * C_) {
        int t = idx / (32 * C_);
        int r = idx % (32 * C_);
        int oc = r / C_, c = r % C_;
        float v = (oc < 18) ? w_off[(oc * C_ + c) * NTAP + t] : 0.f;
        wOb[idx] = f2bf(v);
    }
}

// ---------------------------------------------------------------------------
// NCHW f32 -> NHWC f32 transpose: x_t[n][y][x][c], row stride 256 B.
// Tile: 64 ch x 64 px through LDS, both sides coalesced.
// ---------------------------------------------------------------------------
__global__ __launch_bounds__(256) void k_tr(const float* __restrict__ x,
                                            float* __restrict__ x_t) {
    __shared__ float T[64][65];
    int b = blockIdx.x;
    int n = b >> 10;              // 1024 blocks/image = 128 y * 8 xchunks
    int rem = b & 1023;
    int y = rem >> 3;
    int x0 = (rem & 7) << 6;
    int tid = threadIdx.x;
    int q = tid >> 6, r = tid & 63;

    const float* xp = x + ((size_t)(n * C_) * H_ + y) * W_ + x0;
    #pragma unroll
    for (int k = 0; k < 16; k++) {
        int c = k * 4 + q;
        T[c][r] = xp[(size_t)c * HW_ + r];
    }
    __syncthreads();
    float* op = x_t + ((size_t)(n * H_ + y) * W_ + x0) * 64;
    #pragma unroll
    for (int k = 0; k < 16; k++) {
        int px = k * 4 + q;
        op[(size_t)px * 64 + r] = T[r][px];
    }
}

// ---------------------------------------------------------------------------
// Offset conv as MFMA GEMM: M=128px/block, K=576 (9 taps x 64c), N=32 (18 used)
// Per ROW i (3 of them): stage a 130-px halo strip once, run the 3 j-taps as
// shifted LDS reads -> x read 3x less than per-tap staging.
// B-fragments direct from global wOb (36 KB, cache resident).
// ---------------------------------------------------------------------------
__global__ __launch_bounds__(256, 8) void k_off_mfma(
        const float* __restrict__ x,
        const unsigned short* __restrict__ wOb,
        const float* __restrict__ b_off,
        float* __restrict__ off_ws) {
    __shared__ __align__(16) char smem[17680];
    char* S2 = smem;              // [130][68] bf16: row rr <-> column xb-1+rr
    float* E = (float*)smem;      // [128][33] f32 = 16896 B (epilogue reuse)

    int tid = threadIdx.x;
    int b = blockIdx.x;
    int n = b & 7;
    int lidx = b >> 3;
    int y = lidx >> 2;
    int xb = (lidx & 3) << 7;
    int lane = tid & 63, wave = tid >> 6;
    int p = tid & 127, cg = tid >> 7;
    int la = lane & 31, kh = lane >> 5;

    f16v acc;
    #pragma unroll
    for (int r = 0; r < 16; r++) acc[r] = 0.f;

    const float* xn = x + (size_t)n * C_ * HW_;

    for (int i = 0; i < 3; i++) {
        int yy = y + i - 1;
        if (yy < 0 || yy >= H_) continue;   // block-uniform; zero-pad rows
        __syncthreads();
        // stage strip: rr = p covers cols xb-1..xb+126; p<2 also rr=128+p
        {
            const float* xr = xn + (size_t)(cg * 32) * HW_ + yy * W_;
            int xx = xb + p - 1;
            bool ok = (xx >= 0) && (xx < W_);
            char* sp = S2 + p * 136 + cg * 64;
            #pragma unroll
            for (int u = 0; u < 16; u++) {
                const float* xq = xr + (size_t)(2 * u) * HW_;
                float v0 = ok ? xq[xx] : 0.f;
                float v1 = ok ? xq[HW_ + xx] : 0.f;
                *(unsigned*)(sp + u * 4) = packbf(v0, v1);
            }
            if (p < 2) {
                int xx2 = xb + 127 + p;
                bool ok2 = (xx2 < W_);
                char* sp2 = S2 + (128 + p) * 136 + cg * 64;
                #pragma unroll
                for (int u = 0; u < 16; u++) {
                    const float* xq = xr + (size_t)(2 * u) * HW_;
                    float v0 = ok2 ? xq[xx2] : 0.f;
                    float v1 = ok2 ? xq[HW_ + xx2] : 0.f;
                    *(unsigned*)(sp2 + u * 4) = packbf(v0, v1);
                }
            }
        }
        __syncthreads();
        // 3 shifted MFMA passes: output px p0 samples col p0+j-1 -> rr=p0+j
        #pragma unroll
        for (int j = 0; j < 3; j++) {
            int t = i * 3 + j;
            const char* ap = S2 + (wave * 32 + la + j) * 136 + kh * 16;
            const char* gb = (const char*)wOb + t * 4096 + la * 128 + kh * 16;
            #pragma unroll
            for (int ks = 0; ks < 4; ks++) {
                s8v a, bf;
                *(long*)&a = *(const long*)ap;
                *((long*)&a + 1) = *(const long*)(ap + 8);
                bf = *(const s8v*)(gb + ks * 32);
                ap += 32;
                acc = __builtin_amdgcn_mfma_f32_32x32x16_bf16(a, bf, acc, 0, 0, 0);
            }
        }
    }
    __syncthreads();
    // epilogue: C/D layout col=lane&31 (och), row=(r&3)+8*(r>>2)+4*(lane>>5) (px)
    {
        int lh = lane >> 5;
        #pragma unroll
        for (int r = 0; r < 16; r++) {
            int pxl = wave * 32 + (r & 3) + 8 * (r >> 2) + 4 * lh;
            E[pxl * 33 + la] = acc[r];
        }
    }
    __syncthreads();
    {
        size_t base = ((size_t)(n * H_ + y) * W_ + xb) * 18;
        #pragma unroll
        for (int k = 0; k < 9; k++) {
            int f = tid + k * 256;
            int pp = f / 18, oc = f % 18;
            off_ws[base + f] = E[pp * 33 + oc] + b_off[oc];
        }
    }
}

// ---------------------------------------------------------------------------
// Bilinear metadata: 4 weights (validity folded) + 4 clamped linear offsets
// ---------------------------------------------------------------------------
__device__ __forceinline__ void bilin_meta(float py, float px,
        float& w00, float& w01, float& w10, float& w11,
        int& o00, int& o01, int& o10, int& o11) {
    float fy0 = floorf(py), fx0 = floorf(px);
    int iy0 = (int)fy0, ix0 = (int)fx0;
    int iy1 = iy0 + 1,  ix1 = ix0 + 1;
    float ly = py - fy0, lx = px - fx0;
    float hy = 1.f - ly, hx = 1.f - lx;
    bool y0ok = (iy0 >= 0) && (iy0 < H_);
    bool y1ok = (iy1 >= 0) && (iy1 < H_);
    bool x0ok = (ix0 >= 0) && (ix0 < W_);
    bool x1ok = (ix1 >= 0) && (ix1 < W_);
    w00 = hy * hx * ((y0ok && x0ok) ? 1.f : 0.f);
    w01 = hy * lx * ((y0ok && x1ok) ? 1.f : 0.f);
    w10 = ly * hx * ((y1ok && x0ok) ? 1.f : 0.f);
    w11 = ly * lx * ((y1ok && x1ok) ? 1.f : 0.f);
    int y0c = min(max(iy0, 0), H_ - 1), y1c = min(max(iy1, 0), H_ - 1);
    int x0c = min(max(ix0, 0), W_ - 1), x1c = min(max(ix1, 0), W_ - 1);
    o00 = y0c * W_ + x0c; o01 = y0c * W_ + x1c;
    o10 = y1c * W_ + x0c; o11 = y1c * W_ + x1c;
}

// ---------------------------------------------------------------------------
// Deformable conv as fused sample+MFMA GEMM: M=128px/block, K=576, N=64.
// Gathers from NHWC x_t: one corner for a lane's 32-ch half = 2 contiguous
// float4 loads (vs 32 scattered dwords in NCHW). 32 dwordx4/thread/tap.
// LDS padded to 36 KB to PIN 4 blocks/CU: per-XCD working front ~34 rows
// ~4.5 MB ~ L2 -- at 5+ blocks the front thrashes L2 (r1/r2: FETCH 3x).
// ---------------------------------------------------------------------------
__global__ __launch_bounds__(256, 4) void k_deform(
        const float* __restrict__ x_t,
        const float* __restrict__ off_ws,
        const unsigned short* __restrict__ wTb,
        const float* __restrict__ b_def,
        float* __restrict__ out) {
    __shared__ __align__(16) char smem[36864];   // used: 17408; pad pins 4 blk/CU
    char* S  = smem;              // [128][68] bf16 = 17408 B
    float* E = (float*)smem;      // [128][33] f32 = 16896 B (epilogue, 2 passes)

    int tid = threadIdx.x;
    int b = blockIdx.x;
    int n = b & 7;                 // image <-> XCD for L2 locality
    int lidx = b >> 3;
    int y = lidx >> 2;
    int xb = (lidx & 3) << 7;
    int lane = tid & 63, wave = tid >> 6;
    int p = tid & 127, cg = tid >> 7;
    int la = lane & 31, kh = lane >> 5;

    f16v acc0, acc1;
    #pragma unroll
    for (int r = 0; r < 16; r++) { acc0[r] = 0.f; acc1[r] = 0.f; }

    const char* xtn = (const char*)(x_t + (size_t)n * HW_ * 64) + cg * 128;
    size_t pix = (size_t)(n * H_ + y) * W_ + xb + p;
    const f2v* offp = (const f2v*)off_ws + pix * 9;
    char* sp = S + p * 136 + cg * 64;

    for (int t = 0; t < NTAP; t++) {
        // meta + corner addresses BEFORE the barrier (offp latency hides)
        f2v od = offp[t];
        float py = (float)(y + (t / 3) - 1) + od[0];
        float pxf = (float)(xb + p + (t % 3) - 1) + od[1];
        float w00, w01, w10, w11;
        int o00, o01, o10, o11;
        bilin_meta(py, pxf, w00, w01, w10, w11, o00, o01, o10, o11);
        const char* a00 = xtn + ((size_t)o00 << 8);
        const char* a01 = xtn + ((size_t)o01 << 8);
        const char* a10 = xtn + ((size_t)o10 << 8);
        const char* a11 = xtn + ((size_t)o11 << 8);

        __syncthreads();           // S readers from prev tap done
        // 4 groups x 8 channels: 8 dense float4 gathers + 32 FMA per group
        #pragma unroll
        for (int g = 0; g < 4; g++) {
            float4 c00a = *(const float4*)(a00 + (g << 5));
            float4 c00b = *(const float4*)(a00 + (g << 5) + 16);
            float4 c01a = *(const float4*)(a01 + (g << 5));
            float4 c01b = *(const float4*)(a01 + (g << 5) + 16);
            float4 c10a = *(const float4*)(a10 + (g << 5));
            float4 c10b = *(const float4*)(a10 + (g << 5) + 16);
            float4 c11a = *(const float4*)(a11 + (g << 5));
            float4 c11b = *(const float4*)(a11 + (g << 5) + 16);
            float v0, v1;
            unsigned u0, u1, u2, u3;
            v0 = w00 * c00a.x; v0 = fmaf(w01, c01a.x, v0);
            v0 = fmaf(w10, c10a.x, v0); v0 = fmaf(w11, c11a.x, v0);
            v1 = w00 * c00a.y; v1 = fmaf(w01, c01a.y, v1);
            v1 = fmaf(w10, c10a.y, v1); v1 = fmaf(w11, c11a.y, v1);
            u0 = packbf(v0, v1);
            v0 = w00 * c00a.z; v0 = fmaf(w01, c01a.z, v0);
            v0 = fmaf(w10, c10a.z, v0); v0 = fmaf(w11, c11a.z, v0);
            v1 = w00 * c00a.w; v1 = fmaf(w01, c01a.w, v1);
            v1 = fmaf(w10, c10a.w, v1); v1 = fmaf(w11, c11a.w, v1);
            u1 = packbf(v0, v1);
            v0 = w00 * c00b.x; v0 = fmaf(w01, c01b.x, v0);
            v0 = fmaf(w10, c10b.x, v0); v0 = fmaf(w11, c11b.x, v0);
            v1 = w00 * c00b.y; v1 = fmaf(w01, c01b.y, v1);
            v1 = fmaf(w10, c10b.y, v1); v1 = fmaf(w11, c11b.y, v1);
            u2 = packbf(v0, v1);
            v0 = w00 * c00b.z; v0 = fmaf(w01, c01b.z, v0);
            v0 = fmaf(w10, c10b.z, v0); v0 = fmaf(w11, c11b.z, v0);
            v1 = w00 * c00b.w; v1 = fmaf(w01, c01b.w, v1);
            v1 = fmaf(w10, c10b.w, v1); v1 = fmaf(w11, c11b.w, v1);
            u3 = packbf(v0, v1);
            *(unsigned long long*)(sp + (g << 4)) =
                (unsigned long long)u0 | ((unsigned long long)u1 << 32);
            *(unsigned long long*)(sp + (g << 4) + 8) =
                (unsigned long long)u2 | ((unsigned long long)u3 << 32);
        }
        __syncthreads();
        // MFMA; B fragments straight from global (L1/L2-resident 72 KB table)
        {
            const char* ap = S + (wave * 32 + la) * 136 + kh * 16;
            const char* gb = (const char*)wTb + t * 8192 + la * 128 + kh * 16;
            #pragma unroll
            for (int ks = 0; ks < 4; ks++) {
                s8v a, b0, b1;
                *(long*)&a = *(const long*)ap;
                *((long*)&a + 1) = *(const long*)(ap + 8);
                b0 = *(const s8v*)(gb + ks * 32);
                b1 = *(const s8v*)(gb + 4096 + ks * 32);
                ap += 32;
                acc0 = __builtin_amdgcn_mfma_f32_32x32x16_bf16(a, b0, acc0, 0, 0, 0);
                acc1 = __builtin_amdgcn_mfma_f32_32x32x16_bf16(a, b1, acc1, 0, 0, 0);
            }
        }
    }
    __syncthreads();
    // two-pass epilogue through E[128][33]: acc0 (co 0..31), then acc1 (32..63)
    {
        int lh = lane >> 5;
        #pragma unroll
        for (int r = 0; r < 16; r++) {
            int pxl = wave * 32 + (r & 3) + 8 * (r >> 2) + 4 * lh;
            E[pxl * 33 + la] = acc0[r];
        }
        __syncthreads();
        {
            int p0 = tid & 63;
            #pragma unroll
            for (int cb = 0; cb < 8; cb++) {
                int co = (cb << 2) + (tid >> 6);    // 0..31
                float bv = b_def[co];
                size_t ob = ((size_t)(n * CO_ + co) * H_ + y) * W_ + xb;
                out[ob + p0]      = E[p0 * 33 + co] + bv;
                out[ob + p0 + 64] = E[(p0 + 64) * 33 + co] + bv;
            }
        }
        __syncthreads();
        #pragma unroll
        for (int r = 0; r < 16; r++) {
            int pxl = wave * 32 + (r & 3) + 8 * (r >> 2) + 4 * lh;
            E[pxl * 33 + la] = acc1[r];
        }
        __syncthreads();
        {
            int p0 = tid & 63;
            #pragma unroll
            for (int cb = 0; cb < 8; cb++) {
                int cl = (cb << 2) + (tid >> 6);    // 0..31
                int co = 32 + cl;
                float bv = b_def[co];
                size_t ob = ((size_t)(n * CO_ + co) * H_ + y) * W_ + xb;
                out[ob + p0]      = E[p0 * 33 + cl] + bv;
                out[ob + p0 + 64] = E[(p0 + 64) * 33 + cl] + bv;
            }
        }
    }
}

// ---------------------------------------------------------------------------
extern "C" void kernel_launch(void* const* d_in, const int* in_sizes, int n_in,
                              void* d_out, int out_size, void* d_ws, size_t ws_size,
                              hipStream_t stream) {
    const float* x     = (const float*)d_in[0];
    const float* w_off = (const float*)d_in[1];
    const float* b_off = (const float*)d_in[2];
    const float* w_def = (const float*)d_in[3];
    const float* b_def = (const float*)d_in[4];
    float* out = (float*)d_out;

    // ws: wTb @0 (72K), wOb @80K (36K), off_ws @256K (37.75 MB),
    //     x_t NHWC f32 @40M (134.2 MB) -> total ~168 MB
    unsigned short* wTb = (unsigned short*)d_ws;
    unsigned short* wOb = (unsigned short*)((char*)d_ws + 80 * 1024);
    float* off_ws       = (float*)((char*)d_ws + 256 * 1024);
    float* x_t          = (float*)((char*)d_ws + (size_t)40 * 1024 * 1024);

    hipLaunchKernelGGL(k_prep_w, dim3(144), dim3(256), 0, stream,
                       w_def, w_off, wTb, wOb);
    hipLaunchKernelGGL(k_tr, dim3(8192), dim3(256), 0, stream, x, x_t);
    hipLaunchKernelGGL(k_off_mfma, dim3(4096), dim3(256), 0, stream,
                       x, wOb, b_off, off_ws);
    hipLaunchKernelGGL(k_deform, dim3(4096), dim3(256), 0, stream,
                       x_t, off_ws, wTb, b_def, out);
}